// Round 7
// baseline (108.461 us; speedup 1.0000x reference)
//
#include <hip/hip_runtime.h>
#include <hip/hip_bf16.h>
#include <stdint.h>

typedef __attribute__((ext_vector_type(8))) short bf16x8;
typedef __attribute__((ext_vector_type(4))) float f32x4;
typedef __attribute__((ext_vector_type(4))) unsigned int u32x4;

__device__ __forceinline__ float u2f(unsigned int u) {
  union { unsigned int i; float f; } c; c.i = u; return c.f;
}
__device__ __forceinline__ unsigned int f2b(float f) {
  union { float f; unsigned int i; } c; c.f = f;
  unsigned int x = c.i;
  return (x + 0x7fffu + ((x >> 16) & 1u)) >> 16;  // RNE to bf16
}

// ================= prep kernel (unchanged from R6) =================
__global__ __launch_bounds__(256) void k_prep(
    const float* __restrict__ shape, const float* __restrict__ w_off,
    const float* __restrict__ x, const float* __restrict__ wd,
    char* __restrict__ desc, unsigned short* __restrict__ xt,
    unsigned short* __restrict__ wp) {
  __shared__ float tile[64][65];
  int bid = blockIdx.x;
  int t = threadIdx.x;
  if (bid < 576) {
    // ---- descriptors (16B): {u32 idx01 (two u16 pos idx), u32 idx23, u32 w01, u32 w23} ----
    int band = bid & 3;
    int rem = bid >> 2;                 // = b*36 + g*9 + kk
    int b = rem / 36, r2 = rem % 36, g = r2 / 9, kk = r2 % 9;
    int ky = kk / 3, kx = kk - ky * 3;
    int ocy = g * 18 + kk * 2;
    float wy[18], wx[18];
#pragma unroll
    for (int i = 0; i < 18; ++i) { wy[i] = w_off[ocy * 18 + i]; wx[i] = w_off[(ocy + 1) * 18 + i]; }
    const float* sp = shape + (size_t)b * 2 * 4096;
    char* dp = desc + (size_t)rem * 4096 * 16;
#pragma unroll
    for (int e = 0; e < 4; ++e) {
      int p = band * 1024 + t * 4 + e;
      int y = p >> 6, xx0 = p & 63;
      float dy = 0.f, dx = 0.f;
#pragma unroll
      for (int ic = 0; ic < 2; ++ic)
#pragma unroll
        for (int kyy = 0; kyy < 3; ++kyy) {
          int yy = y + kyy - 1;
          if (yy < 0 || yy > 63) continue;
#pragma unroll
          for (int kxx = 0; kxx < 3; ++kxx) {
            int xx = xx0 + kxx - 1;
            if (xx < 0 || xx > 63) continue;
            float sv = sp[ic * 4096 + yy * 64 + xx];
            dy += sv * wy[ic * 9 + kyy * 3 + kxx];
            dx += sv * wx[ic * 9 + kyy * 3 + kxx];
          }
        }
      float sy = dy + (float)(y + ky - 1);
      float sx = dx + (float)(xx0 + kx - 1);
      float fy = floorf(sy), fx = floorf(sx);
      float ly = sy - fy, lx = sx - fx;
      int y0 = (int)fy, x0 = (int)fx;
      float vy0 = (y0 >= 0 && y0 <= 63) ? 1.f : 0.f;
      float vy1 = (y0 >= -1 && y0 <= 62) ? 1.f : 0.f;
      float vx0 = (x0 >= 0 && x0 <= 63) ? 1.f : 0.f;
      float vx1 = (x0 >= -1 && x0 <= 62) ? 1.f : 0.f;
      float w00 = (1.f - ly) * (1.f - lx) * vy0 * vx0;
      float w01 = (1.f - ly) * lx * vy0 * vx1;
      float w10 = ly * (1.f - lx) * vy1 * vx0;
      float w11 = ly * lx * vy1 * vx1;
      unsigned int yc0 = (unsigned int)min(max(y0, 0), 63);
      unsigned int yc1 = (unsigned int)min(max(y0 + 1, 0), 63);
      unsigned int xc0 = (unsigned int)min(max(x0, 0), 63);
      unsigned int xc1 = (unsigned int)min(max(x0 + 1, 0), 63);
      u32x4 d;
      d[0] = (yc0 * 64 + xc0) | ((yc0 * 64 + xc1) << 16);
      d[1] = (yc1 * 64 + xc0) | ((yc1 * 64 + xc1) << 16);
      d[2] = f2b(w00) | (f2b(w01) << 16);
      d[3] = f2b(w10) | (f2b(w11) << 16);
      *(u32x4*)(dp + (size_t)p * 16) = d;
    }
  } else if (bid < 1600) {
    // ---- transpose ----
    int id = bid - 576;
    int b = id >> 8, ct = (id >> 6) & 3, pt = id & 63;
    int c0 = ct * 64, p0 = pt * 64;
#pragma unroll
    for (int i = 0; i < 4; ++i) {
      int row = (t >> 4) + i * 16;
      int seg = t & 15;
      float4 v = *(const float4*)&x[(size_t)(b * 256 + c0 + row) * 4096 + p0 + seg * 4];
      tile[row][seg * 4 + 0] = v.x;
      tile[row][seg * 4 + 1] = v.y;
      tile[row][seg * 4 + 2] = v.z;
      tile[row][seg * 4 + 3] = v.w;
    }
    __syncthreads();
    {
      int pl = t >> 2;
      int cs = (t & 3) * 16;
      unsigned int wbuf[8];
#pragma unroll
      for (int j = 0; j < 8; ++j)
        wbuf[j] = f2b(tile[cs + 2 * j][pl]) | (f2b(tile[cs + 2 * j + 1][pl]) << 16);
      unsigned short* dst = xt + (size_t)(b * 4096 + p0 + pl) * 256 + c0 + cs;
      *(u32x4*)(dst) = *(u32x4*)&wbuf[0];
      *(u32x4*)(dst + 8) = *(u32x4*)&wbuf[4];
    }
  } else {
    // ---- weight pack: wp[chunk=kk*4+g][m][c] = wd[m][g*64+c][kk] (linear rows) ----
    int id = (bid - 1600) * 256 + t;
    int m = id >> 8, ci = id & 255;
    int g = ci >> 6, c = ci & 63;
    const float* src = wd + (size_t)(m * 256 + ci) * 9;
    float v[9];
#pragma unroll
    for (int kk = 0; kk < 9; ++kk) v[kk] = src[kk];
#pragma unroll
    for (int kk = 0; kk < 9; ++kk)
      wp[(size_t)(kk * 4 + g) * 16384 + m * 64 + c] = (unsigned short)f2b(v[kk]);
  }
}

// ================= main fused kernel =================
// grid 1024: (pair= b,y,xh) x (mb M-half); 256 threads (4 waves) -> 4 blocks/CU.
// Tile M=128 x N=32. A: global->VGPR same-phase (TLP hides). B: LDS dbuf 2x4KB.
// Barrier = lgkmcnt(0) + s_barrier only. Corners 1 phase ahead, desc 2 ahead.
struct CSet { u32x4 v0, v1, v2, v3; unsigned int w01, w23; };

#define DESC_LD(c, dv) do { \
    dv = *(const u32x4*)(descb + (size_t)(((c) & 3) * 9 + ((c) >> 2)) * 65536); \
  } while (0)

#define CORNERS(S, dv, cc) do { \
    unsigned int base_ = (unsigned int)(((cc) & 3) << 7) + cb16; \
    (S).v0 = *(const u32x4*)(xtbB + (((dv)[0] & 0xffffu) << 9) + base_); \
    (S).v1 = *(const u32x4*)(xtbB + (((dv)[0] >> 16) << 9) + base_); \
    (S).v2 = *(const u32x4*)(xtbB + (((dv)[1] & 0xffffu) << 9) + base_); \
    (S).v3 = *(const u32x4*)(xtbB + (((dv)[1] >> 16) << 9) + base_); \
    (S).w01 = (dv)[2]; \
    (S).w23 = (dv)[3]; \
  } while (0)

#define BLEND(S, bbuf) do { \
    float w0_ = u2f((S).w01 << 16), w1_ = u2f((S).w01 & 0xffff0000u); \
    float w2_ = u2f((S).w23 << 16), w3_ = u2f((S).w23 & 0xffff0000u); \
    u32x4 o_; \
    _Pragma("unroll") for (int j_ = 0; j_ < 4; ++j_) { \
      float lo_ = w0_ * u2f((S).v0[j_] << 16) + w1_ * u2f((S).v1[j_] << 16) \
                + w2_ * u2f((S).v2[j_] << 16) + w3_ * u2f((S).v3[j_] << 16); \
      float hi_ = w0_ * u2f((S).v0[j_] & 0xffff0000u) + w1_ * u2f((S).v1[j_] & 0xffff0000u) \
                + w2_ * u2f((S).v2[j_] & 0xffff0000u) + w3_ * u2f((S).v3[j_] & 0xffff0000u); \
      o_[j_] = f2b(lo_) | (f2b(hi_) << 16); \
    } \
    *(u32x4*)((bbuf) + bwr) = o_; \
  } while (0)

#define LOAD_A(c, F) do { \
    const unsigned short* ap_ = wpl + (size_t)(c) * 16384; \
    F##0 = *(const bf16x8*)(ap_); \
    F##1 = *(const bf16x8*)(ap_ + 1024); \
    F##2 = *(const bf16x8*)(ap_ + 32); \
    F##3 = *(const bf16x8*)(ap_ + 1056); \
  } while (0)

#define MFMA8(F, bbuf) do { \
    bf16x8 b0_ = *(const bf16x8*)((bbuf) + brow0 + (kq ^ swz)); \
    bf16x8 b1_ = *(const bf16x8*)((bbuf) + brow1 + (kq ^ swz)); \
    acc00 = __builtin_amdgcn_mfma_f32_16x16x32_bf16(F##0, b0_, acc00, 0, 0, 0); \
    acc01 = __builtin_amdgcn_mfma_f32_16x16x32_bf16(F##0, b1_, acc01, 0, 0, 0); \
    acc10 = __builtin_amdgcn_mfma_f32_16x16x32_bf16(F##1, b0_, acc10, 0, 0, 0); \
    acc11 = __builtin_amdgcn_mfma_f32_16x16x32_bf16(F##1, b1_, acc11, 0, 0, 0); \
    bf16x8 b2_ = *(const bf16x8*)((bbuf) + brow0 + ((64 + kq) ^ swz)); \
    bf16x8 b3_ = *(const bf16x8*)((bbuf) + brow1 + ((64 + kq) ^ swz)); \
    acc00 = __builtin_amdgcn_mfma_f32_16x16x32_bf16(F##2, b2_, acc00, 0, 0, 0); \
    acc01 = __builtin_amdgcn_mfma_f32_16x16x32_bf16(F##2, b3_, acc01, 0, 0, 0); \
    acc10 = __builtin_amdgcn_mfma_f32_16x16x32_bf16(F##3, b2_, acc10, 0, 0, 0); \
    acc11 = __builtin_amdgcn_mfma_f32_16x16x32_bf16(F##3, b3_, acc11, 0, 0, 0); \
  } while (0)

#define BAR() do { \
    asm volatile("s_waitcnt lgkmcnt(0)" ::: "memory"); \
    __builtin_amdgcn_s_barrier(); \
  } while (0)

// Phase(c): A(c)->regs (same-phase use, TLP hides); issue corners(c+2); load desc(c+3);
// blend corners(c+1) -> buf[(c+1)&1]; MFMA A(c) x buf[c&1]; barrier. Tail indices clamped.
#define PHASE(c, F, Sfill, Sblend, dvUse, dvFill, Bmfma, Bblend) do { \
    LOAD_A(c, F); \
    { int cc2_ = (c) + 2 < 36 ? (c) + 2 : 35; CORNERS(Sfill, dvUse, cc2_); } \
    { int cc3_ = (c) + 3 < 36 ? (c) + 3 : 35; DESC_LD(cc3_, dvFill); } \
    BLEND(Sblend, Bblend); \
    MFMA8(F, Bmfma); \
    BAR(); \
  } while (0)

__global__ __launch_bounds__(256, 4) void k_deform_main(
    const unsigned short* __restrict__ xt, const unsigned short* __restrict__ wp,
    const char* __restrict__ desc, float* __restrict__ out) {
  __shared__ __align__(16) char lds[8192];  // B0, B1: 4KB each
  const int t = threadIdx.x;
  const int l = t & 63;
  const int wid = t >> 6;                    // 0..3 (m-slice within half)

  // pair-preserving XCD chunked swizzle: mb 0/1 of a pair stay adjacent (same XCD)
  int orig = blockIdx.x;
  const int pid = orig >> 1;                 // 0..511
  const int mb = orig & 1;
  const int pswz = (pid & 7) * 64 + (pid >> 3);
  const int xh = pswz & 1;
  const int rowid = pswz >> 1;               // 0..255
  const int b = rowid >> 6;
  const int y = rowid & 63;

  const int p = t >> 3;                      // local position 0..31
  const int oc = t & 7;                      // channel octet
  const unsigned int cb16 = oc * 16;
  const int bwr = p * 128 + ((oc * 16) ^ ((p & 7) << 4));

  const int lm = l & 15;
  const int kq = (l >> 4) << 4;
  const int swz = (lm & 7) << 4;
  const int brow0 = lm * 128;
  const int brow1 = brow0 + 2048;

  f32x4 acc00 = {}, acc01 = {}, acc10 = {}, acc11 = {};

  const char* descb = desc + (size_t)(b * 36 * 4096 + y * 64 + xh * 32 + p) * 16;
  const char* xtbB = (const char*)(xt + (size_t)b * 4096 * 256);
  const unsigned short* wpl = wp + (size_t)(mb * 128 + wid * 32 + lm) * 64 + ((l >> 4) << 3);

  char* ldsB0 = lds;
  char* ldsB1 = lds + 4096;

  bf16x8 FA0, FA1, FA2, FA3, FB0, FB1, FB2, FB3;
  CSet SA, SB;
  u32x4 dvA, dvB;

  // ---- prologue: buf0 = B(0); SB = corners(1) in flight; dvA = desc(2) ----
  {
    u32x4 d0, d1;
    DESC_LD(0, d0);
    DESC_LD(1, d1);
    DESC_LD(2, dvA);
    CSet St;
    CORNERS(St, d0, 0);
    CORNERS(SB, d1, 1);
    BLEND(St, ldsB0);
    BAR();
  }

  // ---- 36 uniform phases, 2-phase static rotation ----
  for (int pr = 0; pr < 18; ++pr) {
    const int c = pr * 2;
    PHASE(c,     FA, SA, SB, dvA, dvB, ldsB0, ldsB1);   // even
    PHASE(c + 1, FB, SB, SA, dvB, dvA, ldsB1, ldsB0);   // odd
  }

  // ---- epilogue: ReLU + fp32 store ----
  const int lm4 = (l >> 4) << 2;
  float* ob = out + (size_t)(b * 256 + mb * 128 + wid * 32) * 4096 + y * 64 + xh * 32;
#pragma unroll
  for (int r = 0; r < 4; ++r) {
    ob[(size_t)(lm4 + r) * 4096 + lm] = fmaxf(acc00[r], 0.f);
    ob[(size_t)(lm4 + r) * 4096 + 16 + lm] = fmaxf(acc01[r], 0.f);
    ob[(size_t)(16 + lm4 + r) * 4096 + lm] = fmaxf(acc10[r], 0.f);
    ob[(size_t)(16 + lm4 + r) * 4096 + 16 + lm] = fmaxf(acc11[r], 0.f);
  }
}

extern "C" void kernel_launch(void* const* d_in, const int* in_sizes, int n_in,
                              void* d_out, int out_size, void* d_ws, size_t ws_size,
                              hipStream_t stream) {
  const float* x     = (const float*)d_in[0];
  const float* shape = (const float*)d_in[1];
  const float* w_off = (const float*)d_in[2];
  const float* w_def = (const float*)d_in[3];
  float* out = (float*)d_out;
  char* ws = (char*)d_ws;

  char* desc          = ws;                                          // 9,437,184 B
  unsigned short* xt  = (unsigned short*)(ws + 9437184);             // 8,388,608 B
  unsigned short* wpk = (unsigned short*)(ws + 9437184 + 8388608);   // 1,179,648 B

  k_prep<<<1856, 256, 0, stream>>>(shape, w_off, x, w_def, desc, xt, wpk);
  k_deform_main<<<1024, 256, 0, stream>>>(xt, wpk, desc, out);
}